// Round 5
// baseline (187.482 us; speedup 1.0000x reference)
//
#include <hip/hip_runtime.h>

#define HW   262144   // 512*512
#define HW4  65536    // HW/4
#define NSEG 256
#define NB   8

typedef __attribute__((ext_vector_type(4))) float f32x4;
typedef __attribute__((ext_vector_type(8))) short s16x8;

__device__ __forceinline__ unsigned f2bf(float f) {   // fp32 -> bf16 (RNE)
  unsigned u = __float_as_uint(f);
  return (u + 0x7FFFu + ((u >> 16) & 1u)) >> 16;
}

// -------- Kernel 1: per-(batch,segment) moments via MFMA one-hot ----------
// D[m][s] += A[m][k] * B[k][s]; A = 10 moment rows (bf16), B = one-hot(label)
// built in registers from staged labels. LDS layout: per-wave 64 chunks of
// 96 B (80 B = 10 moments x 4 px bf16, 16 B = int4 labels). A-frag reads are
// 2x ds_read_b64 with <=2-way bank aliasing (free); label reads broadcast.
// Per-block phased LDS reduce -> coalesced global atomic flush into acc.
__global__ __launch_bounds__(256) void k_moments(const float* __restrict__ x,
                                                 const int* __restrict__ labels,
                                                 float* __restrict__ acc) {
  __shared__ __align__(16) char smem[4][6176];   // 64*96 + 32 pad per wave
  const int t = threadIdx.x, w = t >> 6, lane = t & 63;
  const int b = blockIdx.x >> 8, chunk = blockIdx.x & 255;  // 256 blocks/batch
  char* stage = smem[w];
  const int q = lane >> 4, n0 = lane & 15;

  const float4* __restrict__ x4 = (const float4*)(x + (size_t)b * 3 * HW);
  const int4*  __restrict__ l4  = (const int4*)(labels + (size_t)b * HW);

  const int g = chunk * 256 + w * 64 + lane;   // float4 idx in channel plane
  float4 a0 = x4[g];
  float4 a1 = x4[HW4 + g];
  float4 a2 = x4[2 * HW4 + g];
  int4  lb  = l4[g];

  float c0[4] = {a0.x, a0.y, a0.z, a0.w};
  float c1[4] = {a1.x, a1.y, a1.z, a1.w};
  float c2[4] = {a2.x, a2.y, a2.z, a2.w};
  float P[10][4];
  #pragma unroll
  for (int k = 0; k < 4; ++k) {
    P[0][k] = 1.f;
    P[1][k] = c0[k];          P[2][k] = c1[k];          P[3][k] = c2[k];
    P[4][k] = c0[k] * c0[k];  P[5][k] = c1[k] * c1[k];  P[6][k] = c2[k] * c2[k];
    P[7][k] = c0[k] * c1[k];  P[8][k] = c0[k] * c2[k];  P[9][k] = c1[k] * c2[k];
  }
  // store this lane's 96-B chunk: moments m at offset m*8 (4 bf16), labels @80
  char* ck = stage + lane * 96;
  #pragma unroll
  for (int m = 0; m < 10; m += 2) {
    uint4 v;
    v.x = f2bf(P[m][0])     | (f2bf(P[m][1]) << 16);
    v.y = f2bf(P[m][2])     | (f2bf(P[m][3]) << 16);
    v.z = f2bf(P[m + 1][0]) | (f2bf(P[m + 1][1]) << 16);
    v.w = f2bf(P[m + 1][2]) | (f2bf(P[m + 1][3]) << 16);
    *(uint4*)(ck + m * 8) = v;
  }
  *(int4*)(ck + 80) = lb;
  // same-wave LDS ops execute in order; readers below only touch this wave's
  // region (R4 precedent) -> no barrier.

  f32x4 accv[16];
  #pragma unroll
  for (int i = 0; i < 16; ++i) accv[i] = (f32x4){0.f, 0.f, 0.f, 0.f};

  #pragma unroll
  for (int c = 0; c < 8; ++c) {
    const int W0 = c * 8 + 2 * q;
    uint2 lo = *(uint2*)(stage + W0 * 96 + n0 * 8);        // m=n0, px j=0..3
    uint2 hi = *(uint2*)(stage + (W0 + 1) * 96 + n0 * 8);  // m=n0, px j=4..7
    uint4 au; au.x = lo.x; au.y = lo.y; au.z = hi.x; au.w = hi.y;
    s16x8 af = __builtin_bit_cast(s16x8, au);
    int4 lA = *(int4*)(stage + W0 * 96 + 80);        // broadcast reads
    int4 lB = *(int4*)(stage + (W0 + 1) * 96 + 80);
    int lv[8] = {lA.x, lA.y, lA.z, lA.w, lB.x, lB.y, lB.z, lB.w};
    unsigned mk[8];
    #pragma unroll
    for (int j = 0; j < 8; ++j) {
      int d = lv[j] - n0;
      unsigned hit = (((d & 15) == 0) && ((unsigned)d < 256u)) ? 1u : 0u;
      mk[j] = hit << (((unsigned)d >> 4) & 31u);
    }
    unsigned M01 = mk[0] | (mk[1] << 16);
    unsigned M23 = mk[2] | (mk[3] << 16);
    unsigned M45 = mk[4] | (mk[5] << 16);
    unsigned M67 = mk[6] | (mk[7] << 16);
    #pragma unroll
    for (int tl = 0; tl < 16; ++tl) {
      uint4 bi;
      bi.x = ((M01 >> tl) & 0x00010001u) * 0x3F80u;
      bi.y = ((M23 >> tl) & 0x00010001u) * 0x3F80u;
      bi.z = ((M45 >> tl) & 0x00010001u) * 0x3F80u;
      bi.w = ((M67 >> tl) & 0x00010001u) * 0x3F80u;
      s16x8 bf = __builtin_bit_cast(s16x8, bi);
      accv[tl] = __builtin_amdgcn_mfma_f32_16x16x32_bf16(af, bf, accv[tl], 0, 0, 0);
    }
  }

  // phased cross-wave reduce: D row m=q*4+r, col s=tl*16+n0
  __syncthreads();
  float* red = (float*)smem;   // 2560 floats, aliases stage regions
  #pragma unroll
  for (int ph = 0; ph < 4; ++ph) {
    if (w == ph) {
      #pragma unroll
      for (int tl = 0; tl < 16; ++tl)
        #pragma unroll
        for (int r = 0; r < 4; ++r) {
          const int m = q * 4 + r;
          if (m < 10) {
            const int idx = m * 256 + tl * 16 + n0;
            red[idx] = (ph == 0 ? 0.f : red[idx]) + accv[tl][r];
          }
        }
    }
    __syncthreads();
  }

  float* ab = acc + b * 2560;
  for (int i = t; i < 2560; i += 256)
    unsafeAtomicAdd(&ab[i], red[i]);
}

// -------- Kernel 2: moments -> mean/std -> reduce_conv -> L2 normalize ----
__global__ __launch_bounds__(256) void k_stats(const float* __restrict__ acc,
                                               const float* __restrict__ W_pix,
                                               const float* __restrict__ b_pix,
                                               const float* __restrict__ W_red,
                                               const float* __restrict__ b_red,
                                               float* __restrict__ rn) {
  __shared__ float wred[64 * 129];
  __shared__ float comb[4][132];
  const int t = threadIdx.x;

  for (int j4 = t; j4 < 2048; j4 += 256) {
    const int row = j4 >> 5;
    const int c4  = (j4 & 31) << 2;
    float4 v = ((const float4*)W_red)[j4];
    float* d = &wred[row * 129 + c4];
    d[0] = v.x; d[1] = v.y; d[2] = v.z; d[3] = v.w;
  }
  __syncthreads();

  const int w = t >> 6;
  const int f = t & 63;
  const int seg = blockIdx.x * 4 + w;
  const int b = seg >> 8;
  const int s = seg & 255;

  const float* a = acc + b * (10 * NSEG);
  const float N   = fmaxf(a[0 * NSEG + s], 1.0f);
  const float S0  = a[1 * NSEG + s];
  const float S1  = a[2 * NSEG + s];
  const float S2  = a[3 * NSEG + s];
  const float M00 = a[4 * NSEG + s];
  const float M11 = a[5 * NSEG + s];
  const float M22 = a[6 * NSEG + s];
  const float M01 = a[7 * NSEG + s];
  const float M02 = a[8 * NSEG + s];
  const float M12 = a[9 * NSEG + s];

  const float w0 = W_pix[f * 3 + 0];
  const float w1 = W_pix[f * 3 + 1];
  const float w2 = W_pix[f * 3 + 2];
  const float bf = b_pix[f];

  const float wS   = w0 * S0 + w1 * S1 + w2 * S2;
  const float mean = (wS + N * bf) / N;
  const float ssq  = w0 * w0 * M00 + w1 * w1 * M11 + w2 * w2 * M22
                   + 2.f * (w0 * w1 * M01 + w0 * w2 * M02 + w1 * w2 * M12)
                   + 2.f * bf * wS + N * bf * bf;
  const float var  = ssq / N - mean * mean;
  const float stdv = sqrtf(fmaxf(var, 1e-6f));

  comb[w][f]      = mean;
  comb[w][64 + f] = stdv;
  __syncthreads();

  float r = b_red[f];
  const float* wr = &wred[f * 129];
  const float* cb = comb[w];
  for (int g = 0; g < 128; ++g) r += wr[g] * cb[g];

  float sq = r * r;
  #pragma unroll
  for (int off = 32; off > 0; off >>= 1) sq += __shfl_xor(sq, off, 64);
  const float inv = 1.0f / fmaxf(sqrtf(sq), 1e-12f);

  rn[(size_t)seg * 64 + f] = r * inv;
}

// -------- Kernel 3: sim = rn rn^T, fused conv1x1 + BN(eval) + ReLU --------
__global__ __launch_bounds__(256) void k_sim(const float* __restrict__ rn,
                                             float* __restrict__ out,
                                             const float* __restrict__ w_sim,
                                             const float* __restrict__ b_sim,
                                             const float* __restrict__ bn_g,
                                             const float* __restrict__ bn_b,
                                             const float* __restrict__ bn_m,
                                             const float* __restrict__ bn_v) {
  __shared__ float A[64 * 65];
  __shared__ float Bt[64 * 65];
  const int t  = threadIdx.x;
  const int b  = blockIdx.x >> 4;
  const int ti = (blockIdx.x >> 2) & 3;
  const int tj = blockIdx.x & 3;

  const float4* rn4 = (const float4*)(rn + (size_t)b * NSEG * 64);
  for (int j4 = t; j4 < 1024; j4 += 256) {
    const int row = j4 >> 4;
    const int c4  = (j4 & 15) << 2;
    float4 va = rn4[(ti * 64 + row) * 16 + (j4 & 15)];
    float* da = &A[row * 65 + c4];
    da[0] = va.x; da[1] = va.y; da[2] = va.z; da[3] = va.w;
    float4 vb = rn4[(tj * 64 + row) * 16 + (j4 & 15)];
    float* db = &Bt[row * 65 + c4];
    db[0] = vb.x; db[1] = vb.y; db[2] = vb.z; db[3] = vb.w;
  }
  __syncthreads();

  const int tx = t & 15;
  const int ty = t >> 4;
  float acc[4][4] = {{0.f}};
  for (int k = 0; k < 64; ++k) {
    float av[4], bv[4];
    #pragma unroll
    for (int i = 0; i < 4; ++i) av[i] = A[(ty * 4 + i) * 65 + k];
    #pragma unroll
    for (int j = 0; j < 4; ++j) bv[j] = Bt[(tx * 4 + j) * 65 + k];
    #pragma unroll
    for (int i = 0; i < 4; ++i)
      #pragma unroll
      for (int j = 0; j < 4; ++j) acc[i][j] += av[i] * bv[j];
  }

  const float invsd = 1.0f / sqrtf(bn_v[0] + 1e-5f);
  const float scale = w_sim[0] * bn_g[0] * invsd;
  const float shift = (b_sim[0] - bn_m[0]) * bn_g[0] * invsd + bn_b[0];

  #pragma unroll
  for (int i = 0; i < 4; ++i) {
    float4 v;
    v.x = fmaxf(acc[i][0] * scale + shift, 0.f);
    v.y = fmaxf(acc[i][1] * scale + shift, 0.f);
    v.z = fmaxf(acc[i][2] * scale + shift, 0.f);
    v.w = fmaxf(acc[i][3] * scale + shift, 0.f);
    const int base = b * 65536 + (ti * 64 + ty * 4 + i) * 256 + tj * 64;
    ((float4*)out)[(base >> 2) + tx] = v;
  }
}

extern "C" void kernel_launch(void* const* d_in, const int* in_sizes, int n_in,
                              void* d_out, int out_size, void* d_ws, size_t ws_size,
                              hipStream_t stream) {
  (void)in_sizes; (void)n_in; (void)out_size; (void)ws_size;
  const float* x      = (const float*)d_in[0];
  const int*   labels = (const int*)d_in[1];
  const float* W_pix  = (const float*)d_in[3];
  const float* b_pix  = (const float*)d_in[4];
  const float* W_red  = (const float*)d_in[5];
  const float* b_red  = (const float*)d_in[6];
  const float* w_sim  = (const float*)d_in[7];
  const float* b_sim  = (const float*)d_in[8];
  const float* bn_g   = (const float*)d_in[9];
  const float* bn_b   = (const float*)d_in[10];
  const float* bn_m   = (const float*)d_in[11];
  const float* bn_v   = (const float*)d_in[12];
  float* out = (float*)d_out;

  float* acc = (float*)d_ws;                 // 8*10*256 floats = 80 KB
  float* rn  = acc + NB * 10 * NSEG;         // 8*256*64 floats = 512 KB

  hipMemsetAsync(acc, 0, NB * 10 * NSEG * sizeof(float), stream);
  k_moments<<<dim3(2048), dim3(256), 0, stream>>>(x, labels, acc);
  k_stats<<<dim3(512), dim3(256), 0, stream>>>(acc, W_pix, b_pix, W_red, b_red, rn);
  k_sim<<<dim3(128), dim3(256), 0, stream>>>(rn, out, w_sim, b_sim, bn_g, bn_b, bn_m, bn_v);
}